// Round 10
// baseline (808.655 us; speedup 1.0000x reference)
//
#include <hip/hip_runtime.h>

typedef unsigned short u16;
typedef __attribute__((ext_vector_type(8))) short short8;
typedef __attribute__((ext_vector_type(4))) float f32x4;
typedef __attribute__((ext_vector_type(4))) u16 ushort4v;
typedef __attribute__((ext_vector_type(8))) u16 ushort8v;

#define DIM 2048
#define HID 5632
#define F2  11264
#define TTOT 8192

#define GLD(g, l) __builtin_amdgcn_global_load_lds(                       \
    (const __attribute__((address_space(1))) void*)(g),                   \
    (__attribute__((address_space(3))) void*)(l), 16, 0, 0)

__device__ __forceinline__ u16 f2bf(float f) {
  unsigned int u = __builtin_bit_cast(unsigned int, f);
  u += 0x7FFFu + ((u >> 16) & 1u);   // round-to-nearest-even (finite values)
  return (u16)(u >> 16);
}

// ---- weight conversion: w13 fp32 -> bf16, rows PERMUTED so (x1,x3) pairs are
// 16-col groups: new row r: b=r>>5, i=r&31; orig = i<16 ? b*16+i : HID+b*16+(i-16)
__global__ __launch_bounds__(256) void conv_w13(const float* __restrict__ w,
                                                u16* __restrict__ o) {
  int idx = blockIdx.x * 256 + threadIdx.x;          // 0 .. F2*DIM/4-1
  int rnew = idx >> 9;                               // DIM/4 = 512 float4/row
  int dc = (idx & 511) << 2;
  int b = rnew >> 5, ii = rnew & 31;
  int orig = (ii < 16) ? (b * 16 + ii) : (HID + b * 16 + (ii - 16));
  float4 v = *reinterpret_cast<const float4*>(w + (size_t)orig * DIM + dc);
  ushort4v q = {f2bf(v.x), f2bf(v.y), f2bf(v.z), f2bf(v.w)};
  *reinterpret_cast<ushort4v*>(o + (size_t)rnew * DIM + dc) = q;
}

__global__ __launch_bounds__(256) void conv_w2(const float* __restrict__ w,
                                               u16* __restrict__ o) {
  size_t e = ((size_t)blockIdx.x * 256 + threadIdx.x) * 4;
  float4 v = *reinterpret_cast<const float4*>(w + e);
  ushort4v q = {f2bf(v.x), f2bf(v.y), f2bf(v.z), f2bf(v.w)};
  *reinterpret_cast<ushort4v*>(o + e) = q;
}

// ---- per-token quant of x: q = rint(x*s) as bf16 (exact ints), scale = max/127
__global__ __launch_bounds__(256) void quant_x(const float* __restrict__ x,
                                               u16* __restrict__ q,
                                               float* __restrict__ scale) {
  const int t = blockIdx.x;
  const float* xr = x + (size_t)t * DIM;
  const int tid = threadIdx.x;
  float4 a = *reinterpret_cast<const float4*>(xr + tid * 8);
  float4 b = *reinterpret_cast<const float4*>(xr + tid * 8 + 4);
  float v[8] = {a.x, a.y, a.z, a.w, b.x, b.y, b.z, b.w};
  float m = 0.f;
#pragma unroll
  for (int i = 0; i < 8; ++i) m = fmaxf(m, fabsf(v[i]));
#pragma unroll
  for (int off = 32; off; off >>= 1) m = fmaxf(m, __shfl_xor(m, off));
  __shared__ float red[4];
  if ((tid & 63) == 0) red[tid >> 6] = m;
  __syncthreads();
  m = fmaxf(fmaxf(red[0], red[1]), fmaxf(red[2], red[3]));
  m = fmaxf(m, 1e-5f);
  float s = 127.0f / m;
  if (tid == 0) scale[t] = m / 127.0f;
  ushort8v o;
#pragma unroll
  for (int i = 0; i < 8; ++i) {
    float r = fminf(fmaxf(rintf(v[i] * s), -128.f), 127.f);
    o[i] = f2bf(r);
  }
  *reinterpret_cast<ushort8v*>(q + (size_t)t * DIM + tid * 8) = o;
}

// ---- gated row -> rmsnorm -> quant (bf16 ints) + scale
__global__ __launch_bounds__(256) void gate_nq(const float* __restrict__ G,
                                               const float* __restrict__ nw,
                                               u16* __restrict__ q2,
                                               float* __restrict__ s2) {
  const int t = blockIdx.x;
  const float* gr = G + (size_t)t * HID;
  const int tid = threadIdx.x;
  float4 vv[6];
  float ss = 0.f, mx = 0.f;
#pragma unroll
  for (int k = 0; k < 6; ++k) {
    int i = tid + k * 256;
    if (i < 1408) {
      float4 v = *reinterpret_cast<const float4*>(gr + i * 4);
      float4 w4 = *reinterpret_cast<const float4*>(nw + i * 4);
      vv[k] = v;
      ss += v.x * v.x + v.y * v.y + v.z * v.z + v.w * v.w;
      mx = fmaxf(mx, fmaxf(fmaxf(fabsf(v.x * w4.x), fabsf(v.y * w4.y)),
                           fmaxf(fabsf(v.z * w4.z), fabsf(v.w * w4.w))));
    }
  }
#pragma unroll
  for (int off = 32; off; off >>= 1) {
    ss += __shfl_xor(ss, off);
    mx = fmaxf(mx, __shfl_xor(mx, off));
  }
  __shared__ float rs[4], rm[4];
  if ((tid & 63) == 0) { rs[tid >> 6] = ss; rm[tid >> 6] = mx; }
  __syncthreads();
  ss = rs[0] + rs[1] + rs[2] + rs[3];
  mx = fmaxf(fmaxf(rm[0], rm[1]), fmaxf(rm[2], rm[3]));
  float rinv = 1.0f / sqrtf(ss * (1.0f / 5632.0f) + 1e-5f);
  float mi = fmaxf(mx * rinv, 1e-5f);
  float s = 127.0f / mi;
  if (tid == 0) s2[t] = mi / 127.0f;
  float fs = rinv * s;
#pragma unroll
  for (int k = 0; k < 6; ++k) {
    int i = tid + k * 256;
    if (i < 1408) {
      float4 v = vv[k];
      float4 w4 = *reinterpret_cast<const float4*>(nw + i * 4);
      ushort4v o;
      o.x = f2bf(fminf(fmaxf(rintf(v.x * w4.x * fs), -128.f), 127.f));
      o.y = f2bf(fminf(fmaxf(rintf(v.y * w4.y * fs), -128.f), 127.f));
      o.z = f2bf(fminf(fmaxf(rintf(v.z * w4.z * fs), -128.f), 127.f));
      o.w = f2bf(fminf(fmaxf(rintf(v.w * w4.w * fs), -128.f), 127.f));
      *reinterpret_cast<ushort4v*>(q2 + (size_t)t * HID + i * 4) = o;
    }
  }
}

// ============================================================================
// 256x256 GEMM, 2 phases/K-tile with REGISTER-PIPELINED fragment reads:
// phase P(i) = { issue 12 ds_reads for P(i+1)'s frags; issue 4 stage-GLDs;
//   lgkmcnt(12) [waits P(i-1)'s reads only -- drained under P(i-1)'s MFMA] +
//   sched_barrier(0) [rule 18]; 32 MFMA on P(i)'s frags; vmcnt(4); barrier }.
// At 2-phase granularity LDS drain (~1150cyc/CU) ~= MFMA burst (~1184cyc) so
// the one-phase-ahead prefetch hides the whole drain (r5's 4-phase attempt
// couldn't: 600cyc window < 1150 drain).
// Hazards: stage-overwrite keeps 1-barrier separation (region's last reads
// complete at the following phase's lgkmcnt(12), before its barrier; the
// overwriting stage issues >=1 barrier later). Read-residency: P(i) reads data
// staged at P(i-2); vmcnt(4) at P(i-1) end waits P(i-2)'s 4 stage-GLDs
// (outstanding = own 4 + prev 4). Tail: vmcnt(0) at P(2NT-3) covers kk1[NT-1].
// MFMA order identical to round 9 -> bit-identical output.
// LDS 128KB: [db][A/B][kk][256 rows][32 u16]; chunk slot q^((r>>1)&3)
// (both-sides permutation; measured 0 bank conflicts). 512 thr = 8 waves
// (2M x 4N); per-wave 128x64. GATE=1: gated epilogue, C is [M,N/2].
// ============================================================================
template <int GATE, int N, int K, int Ntiles>
__global__ __launch_bounds__(512, 2) void gemm8(
    const u16* __restrict__ A, const u16* __restrict__ B,
    const float* __restrict__ rowscale, float* __restrict__ C) {
  __shared__ __attribute__((aligned(16))) u16 lds[2][2][2][256 * 32];
  constexpr int NT = K >> 6;            // even: 32 (K=2048), 88 (K=5632)
  const int nwg = gridDim.x;
  const int orig = blockIdx.x;
  const int qq = nwg >> 3, rr = nwg & 7, xcd = orig & 7, sidx = orig >> 3;
  const int wg = (xcd < rr ? xcd * (qq + 1) : rr * (qq + 1) + (xcd - rr) * qq) + sidx;
  const int mt = wg / Ntiles, nt = wg % Ntiles;

  const int tid = threadIdx.x;
  const int wid = tid >> 6, lane = tid & 63;
  const int wm = wid >> 2, wn = wid & 3;
  const int c16 = lane & 15, q4 = lane >> 4;
  const int rA_base = wm * 128 + c16;
  const int rB_base = wn * 64 + c16;
  const int caf = (q4 ^ ((lane >> 1) & 3)) << 3;  // chunk slot q4^((row>>1)&3)

  const int sr = tid >> 2;
  const int scol = ((tid & 3) ^ ((tid >> 3) & 3)) << 3;
  const u16* Ar = A + ((size_t)mt * 256 + sr) * K + scol;
  const u16* Br = B + ((size_t)nt * 256 + sr) * K + scol;
  constexpr size_t rstep = (size_t)128 * K;

  f32x4 acc[8][4];
#pragma unroll
  for (int m = 0; m < 8; ++m)
#pragma unroll
    for (int n = 0; n < 4; ++n) acc[m][n] = f32x4{0.f, 0.f, 0.f, 0.f};

#define STAGE(MAT, KK, T, BUF)                                                \
  {                                                                           \
    const u16* g = ((MAT) ? Br : Ar) + (T) * 64 + (KK) * 32;                  \
    u16* l = &lds[BUF][MAT][KK][wid << 9];                                    \
    GLD(g, l);                                                                \
    GLD(g + rstep, l + 4096);                                                 \
  }
#define LDA(DB, KK, MH, AF)                                                   \
  _Pragma("unroll") for (int m = 0; m < 4; ++m)                               \
      AF[m] = *reinterpret_cast<const short8*>(                               \
          &lds[DB][0][KK][(rA_base + ((MH) * 4 + m) * 16) * 32 + caf]);
#define LDB(DB, KK, BF)                                                       \
  _Pragma("unroll") for (int n = 0; n < 4; ++n)                               \
      BF[n] = *reinterpret_cast<const short8*>(                               \
          &lds[DB][1][KK][(rB_base + n * 16) * 32 + caf]);
#define MFMA32(AF0, AF1, BF)                                                  \
  __builtin_amdgcn_s_setprio(1);                                              \
  _Pragma("unroll") for (int m = 0; m < 4; ++m)                               \
      _Pragma("unroll") for (int n = 0; n < 4; ++n)                           \
          acc[m][n] = __builtin_amdgcn_mfma_f32_16x16x32_bf16(                \
              AF0[m], BF[n], acc[m][n], 0, 0, 0);                             \
  _Pragma("unroll") for (int m = 0; m < 4; ++m)                               \
      _Pragma("unroll") for (int n = 0; n < 4; ++n)                           \
          acc[4 + m][n] = __builtin_amdgcn_mfma_f32_16x16x32_bf16(            \
              AF1[m], BF[n], acc[4 + m][n], 0, 0, 0);                         \
  __builtin_amdgcn_s_setprio(0);                                              \
  __builtin_amdgcn_sched_barrier(0);
#define BARR asm volatile("s_barrier" ::: "memory")
#define VMC(NN) asm volatile("s_waitcnt vmcnt(" #NN ")" ::: "memory")
#define LGKM12 do { asm volatile("s_waitcnt lgkmcnt(12)" ::: "memory");       \
                    __builtin_amdgcn_sched_barrier(0); } while (0)

// Phase: read next-set frags from lds[NDB][*][NKK]; optional stage; wait prev
// reads; MFMA current set; vmcnt; barrier.  (sets are NAMED arrays, rule 20)
#define PH(NDB, NKK, RB, RA0, RA1, CA0, CA1, CB, DOSTG, STKK, STT, STBUF, VM) \
  {                                                                           \
    LDB(NDB, NKK, RB)                                                         \
    LDA(NDB, NKK, 0, RA0)                                                     \
    LDA(NDB, NKK, 1, RA1)                                                     \
    if (DOSTG) { STAGE(0, STKK, STT, STBUF) STAGE(1, STKK, STT, STBUF) }      \
    LGKM12;                                                                   \
    MFMA32(CA0, CA1, CB)                                                      \
    VM;                                                                       \
    BARR;                                                                     \
  }

  // prologue: tile0 (kk0,kk1)->buf0, tile1 kk0 -> buf1 (12 GLDs);
  // vmcnt(4) -> tile0 resident. Then prime set-A with tile0-kk0 frags.
  STAGE(1, 0, 0, 0) STAGE(0, 0, 0, 0) STAGE(1, 1, 0, 0) STAGE(0, 1, 0, 0)
  STAGE(1, 0, 1, 1) STAGE(0, 0, 1, 1)
  VMC(4);
  BARR;

  short8 bA[4], a0A[4], a1A[4], bB[4], a0B[4], a1B[4];
  LDB(0, 0, bA) LDA(0, 0, 0, a0A) LDA(0, 0, 1, a1A)

#pragma unroll 1
  for (int u = 0; u < NT - 2; u += 2) {
    // tile u (db0): consume kk0 | read kk1(buf0) | stage kk1[u+1]->buf1
    PH(0, 1, bB, a0B, a1B, a0A, a1A, bA, 1, 1, u + 1, 1, VMC(4))
    //            consume kk1 | read kk0[u+1](buf1) | stage kk0[u+2]->buf0
    PH(1, 0, bA, a0A, a1A, a0B, a1B, bB, 1, 0, u + 2, 0, VMC(4))
    // tile u+1 (db1): consume kk0 | read kk1(buf1) | stage kk1[u+2]->buf0
    PH(1, 1, bB, a0B, a1B, a0A, a1A, bA, 1, 1, u + 2, 0, VMC(4))
    //            consume kk1 | read kk0[u+2](buf0) | stage kk0[u+3]->buf1
    PH(0, 0, bA, a0A, a1A, a0B, a1B, bB, 1, 0, u + 3, 1, VMC(4))
  }
  // tail: tiles NT-2 (db0), NT-1 (db1)
  PH(0, 1, bB, a0B, a1B, a0A, a1A, bA, 1, 1, NT - 1, 1, VMC(4))  // stage kk1[NT-1]
  PH(1, 0, bA, a0A, a1A, a0B, a1B, bB, 0, 0, 0, 0, VMC(0))       // read kk0[NT-1]
  // P(2NT-2): read kk1[NT-1]; no stage; no vmcnt; no barrier needed after
  LDB(1, 1, bB) LDA(1, 1, 0, a0B) LDA(1, 1, 1, a1B)
  LGKM12;
  MFMA32(a0A, a1A, bA)
  // P(2NT-1): final consume
  asm volatile("s_waitcnt lgkmcnt(0)" ::: "memory");
  __builtin_amdgcn_sched_barrier(0);
  MFMA32(a0B, a1B, bB)

  // ---- epilogue
  const int mbase0 = mt * 256 + wm * 128;
  if constexpr (GATE == 0) {
#pragma unroll
    for (int m = 0; m < 8; ++m) {
#pragma unroll
      for (int j = 0; j < 4; ++j) {
        const int row = mbase0 + m * 16 + q4 * 4 + j;
        const float sc = rowscale[row];
        float* crow = C + (size_t)row * N + nt * 256 + wn * 64 + c16;
#pragma unroll
        for (int n = 0; n < 4; ++n) crow[n * 16] = acc[m][n][j] * sc;
      }
    }
  } else {
    constexpr int H = N >> 1;
    const int gbase = (nt * 256 + wn * 64) >> 1;
#pragma unroll
    for (int m = 0; m < 8; ++m) {
#pragma unroll
      for (int j = 0; j < 4; ++j) {
        const int row = mbase0 + m * 16 + q4 * 4 + j;
        const float sc = rowscale[row];
        const float s3 = sc * sc * sc;
        float* grow = C + (size_t)row * H + gbase + c16;
#pragma unroll
        for (int p = 0; p < 2; ++p) {
          float a1 = acc[m][2 * p][j];
          float a3 = acc[m][2 * p + 1][j];
          float rl = fmaxf(a1, 0.f);
          grow[p * 16] = rl * rl * a3 * s3;
        }
      }
    }
  }
}

extern "C" void kernel_launch(void* const* d_in, const int* in_sizes, int n_in,
                              void* d_out, int out_size, void* d_ws, size_t ws_size,
                              hipStream_t stream) {
  const float* x = (const float*)d_in[0];
  const float* w13 = (const float*)d_in[1];
  const float* w2 = (const float*)d_in[2];
  const float* nw = (const float*)d_in[3];
  float* out = (float*)d_out;

  char* p = (char*)d_ws;
  u16* w13p = (u16*)p; p += (size_t)F2 * DIM * 2;
  u16* w2b = (u16*)p;  p += (size_t)DIM * HID * 2;
  u16* q2f = (u16*)p;  p += (size_t)TTOT * HID * 2;
  float* s2f = (float*)p; p += (size_t)TTOT * 4;
  const size_t fixed = (size_t)F2 * DIM * 2 + (size_t)DIM * HID * 2 +
                       (size_t)TTOT * HID * 2 + (size_t)TTOT * 4;
  const size_t perTok = (size_t)DIM * 2 + (size_t)HID * 4 + 8;
  int Tc = TTOT;
  while (Tc > 256 && fixed + (size_t)Tc * perTok > ws_size) Tc >>= 1;
  u16* q1 = (u16*)p;        p += (size_t)Tc * DIM * 2;
  float* gated = (float*)p; p += (size_t)Tc * HID * 4;
  float* s1 = (float*)p;

  conv_w13<<<F2 * DIM / 4 / 256, 256, 0, stream>>>(w13, w13p);
  conv_w2<<<DIM * HID / 4 / 256, 256, 0, stream>>>(w2, w2b);

  for (int t0 = 0; t0 < TTOT; t0 += Tc) {
    quant_x<<<Tc, 256, 0, stream>>>(x + (size_t)t0 * DIM, q1, s1);
    gemm8<1, F2, DIM, F2 / 256><<<(Tc / 256) * (F2 / 256), 512, 0, stream>>>(
        q1, w13p, s1, gated);
    gate_nq<<<Tc, 256, 0, stream>>>(gated, nw, q2f + (size_t)t0 * HID, s2f + t0);
  }
  gemm8<0, DIM, HID, DIM / 256><<<(TTOT / 256) * (DIM / 256), 512, 0, stream>>>(
      q2f, w2b, s2f, out);
}

// Round 11
// 599.186 us; speedup vs baseline: 1.3496x; 1.3496x over previous
//
#include <hip/hip_runtime.h>

typedef unsigned short u16;
typedef __attribute__((ext_vector_type(8))) short short8;
typedef __attribute__((ext_vector_type(4))) float f32x4;
typedef __attribute__((ext_vector_type(4))) u16 ushort4v;
typedef __attribute__((ext_vector_type(8))) u16 ushort8v;

#define DIM 2048
#define HID 5632
#define F2  11264
#define TTOT 8192

#define GLD(g, l) __builtin_amdgcn_global_load_lds(                       \
    (const __attribute__((address_space(1))) void*)(g),                   \
    (__attribute__((address_space(3))) void*)(l), 16, 0, 0)

__device__ __forceinline__ u16 f2bf(float f) {
  unsigned int u = __builtin_bit_cast(unsigned int, f);
  u += 0x7FFFu + ((u >> 16) & 1u);   // round-to-nearest-even (finite values)
  return (u16)(u >> 16);
}

// ---- weight conversion: w13 fp32 -> bf16, rows PERMUTED so (x1,x3) pairs are
// 16-col groups: new row r: b=r>>5, i=r&31; orig = i<16 ? b*16+i : HID+b*16+(i-16)
__global__ __launch_bounds__(256) void conv_w13(const float* __restrict__ w,
                                                u16* __restrict__ o) {
  int idx = blockIdx.x * 256 + threadIdx.x;          // 0 .. F2*DIM/4-1
  int rnew = idx >> 9;                               // DIM/4 = 512 float4/row
  int dc = (idx & 511) << 2;
  int b = rnew >> 5, ii = rnew & 31;
  int orig = (ii < 16) ? (b * 16 + ii) : (HID + b * 16 + (ii - 16));
  float4 v = *reinterpret_cast<const float4*>(w + (size_t)orig * DIM + dc);
  ushort4v q = {f2bf(v.x), f2bf(v.y), f2bf(v.z), f2bf(v.w)};
  *reinterpret_cast<ushort4v*>(o + (size_t)rnew * DIM + dc) = q;
}

__global__ __launch_bounds__(256) void conv_w2(const float* __restrict__ w,
                                               u16* __restrict__ o) {
  size_t e = ((size_t)blockIdx.x * 256 + threadIdx.x) * 4;
  float4 v = *reinterpret_cast<const float4*>(w + e);
  ushort4v q = {f2bf(v.x), f2bf(v.y), f2bf(v.z), f2bf(v.w)};
  *reinterpret_cast<ushort4v*>(o + e) = q;
}

// ---- per-token quant of x: q = rint(x*s) as bf16 (exact ints), scale = max/127
__global__ __launch_bounds__(256) void quant_x(const float* __restrict__ x,
                                               u16* __restrict__ q,
                                               float* __restrict__ scale) {
  const int t = blockIdx.x;
  const float* xr = x + (size_t)t * DIM;
  const int tid = threadIdx.x;
  float4 a = *reinterpret_cast<const float4*>(xr + tid * 8);
  float4 b = *reinterpret_cast<const float4*>(xr + tid * 8 + 4);
  float v[8] = {a.x, a.y, a.z, a.w, b.x, b.y, b.z, b.w};
  float m = 0.f;
#pragma unroll
  for (int i = 0; i < 8; ++i) m = fmaxf(m, fabsf(v[i]));
#pragma unroll
  for (int off = 32; off; off >>= 1) m = fmaxf(m, __shfl_xor(m, off));
  __shared__ float red[4];
  if ((tid & 63) == 0) red[tid >> 6] = m;
  __syncthreads();
  m = fmaxf(fmaxf(red[0], red[1]), fmaxf(red[2], red[3]));
  m = fmaxf(m, 1e-5f);
  float s = 127.0f / m;
  if (tid == 0) scale[t] = m / 127.0f;
  ushort8v o;
#pragma unroll
  for (int i = 0; i < 8; ++i) {
    float r = fminf(fmaxf(rintf(v[i] * s), -128.f), 127.f);
    o[i] = f2bf(r);
  }
  *reinterpret_cast<ushort8v*>(q + (size_t)t * DIM + tid * 8) = o;
}

// ---- gated row -> rmsnorm -> quant (bf16 ints) + scale
__global__ __launch_bounds__(256) void gate_nq(const float* __restrict__ G,
                                               const float* __restrict__ nw,
                                               u16* __restrict__ q2,
                                               float* __restrict__ s2) {
  const int t = blockIdx.x;
  const float* gr = G + (size_t)t * HID;
  const int tid = threadIdx.x;
  float4 vv[6];
  float ss = 0.f, mx = 0.f;
#pragma unroll
  for (int k = 0; k < 6; ++k) {
    int i = tid + k * 256;
    if (i < 1408) {
      float4 v = *reinterpret_cast<const float4*>(gr + i * 4);
      float4 w4 = *reinterpret_cast<const float4*>(nw + i * 4);
      vv[k] = v;
      ss += v.x * v.x + v.y * v.y + v.z * v.z + v.w * v.w;
      mx = fmaxf(mx, fmaxf(fmaxf(fabsf(v.x * w4.x), fabsf(v.y * w4.y)),
                           fmaxf(fabsf(v.z * w4.z), fabsf(v.w * w4.w))));
    }
  }
#pragma unroll
  for (int off = 32; off; off >>= 1) {
    ss += __shfl_xor(ss, off);
    mx = fmaxf(mx, __shfl_xor(mx, off));
  }
  __shared__ float rs[4], rm[4];
  if ((tid & 63) == 0) { rs[tid >> 6] = ss; rm[tid >> 6] = mx; }
  __syncthreads();
  ss = rs[0] + rs[1] + rs[2] + rs[3];
  mx = fmaxf(fmaxf(rm[0], rm[1]), fmaxf(rm[2], rm[3]));
  float rinv = 1.0f / sqrtf(ss * (1.0f / 5632.0f) + 1e-5f);
  float mi = fmaxf(mx * rinv, 1e-5f);
  float s = 127.0f / mi;
  if (tid == 0) s2[t] = mi / 127.0f;
  float fs = rinv * s;
#pragma unroll
  for (int k = 0; k < 6; ++k) {
    int i = tid + k * 256;
    if (i < 1408) {
      float4 v = vv[k];
      float4 w4 = *reinterpret_cast<const float4*>(nw + i * 4);
      ushort4v o;
      o.x = f2bf(fminf(fmaxf(rintf(v.x * w4.x * fs), -128.f), 127.f));
      o.y = f2bf(fminf(fmaxf(rintf(v.y * w4.y * fs), -128.f), 127.f));
      o.z = f2bf(fminf(fmaxf(rintf(v.z * w4.z * fs), -128.f), 127.f));
      o.w = f2bf(fminf(fmaxf(rintf(v.w * w4.w * fs), -128.f), 127.f));
      *reinterpret_cast<ushort4v*>(q2 + (size_t)t * HID + i * 4) = o;
    }
  }
}

// ============================================================================
// 256x256 GEMM, 2 phases/K-tile, HALF-PHASE register pipeline (r10 mechanism,
// 3 fewer live frag arrays -> no spill):
// phase P(i) = { issue 4 ds_reads A1(cur); issue 8 ds_reads B+A0 for P(i+1);
//   issue stage GLDs; lgkm(12)+schedbar [in-order DS: guarantees P(i-1)'s 8 =
//   current B/A0]; 16 MFMA (A0,B); lgkm(8)+schedbar [A1 done, drained under
//   burst 1]; 16 MFMA (A1,B); vmcnt(4); barrier }.
// Register cost: 5 named frag arrays (BC,A0C,BN,A0N,A1) = 80 VGPR vs r10's
// 96 -> fits beside 128-reg acc (AGPR) without scratch (r10 spilled: WRITE
// +25MB). Hazards audited: stage regions never overlap same-phase read
// regions; stage->read separation = stage-complete guarantee (next phase's
// vmcnt(4), in-order) + >=1 barrier; prefetch reads target data staged >=3
// barriers earlier. Tail: vmcnt(0) at 2nd-last phase with a stage; final
// phase lgkm(4)/lgkm(0). MFMA order identical -> bit-identical output.
// LDS 128KB: [db][A/B][kk][256 rows][32 u16]; chunk slot q^((r>>1)&3)
// (both-sides permutation; measured 0 bank conflicts). 512 thr = 8 waves
// (2M x 4N); per-wave 128x64. GATE=1: gated epilogue, C is [M,N/2].
// ============================================================================
template <int GATE, int N, int K, int Ntiles>
__global__ __launch_bounds__(512, 2) void gemm8(
    const u16* __restrict__ A, const u16* __restrict__ B,
    const float* __restrict__ rowscale, float* __restrict__ C) {
  __shared__ __attribute__((aligned(16))) u16 lds[2][2][2][256 * 32];
  constexpr int NT = K >> 6;            // even: 32 (K=2048), 88 (K=5632)
  const int nwg = gridDim.x;
  const int orig = blockIdx.x;
  const int qq = nwg >> 3, rr = nwg & 7, xcd = orig & 7, sidx = orig >> 3;
  const int wg = (xcd < rr ? xcd * (qq + 1) : rr * (qq + 1) + (xcd - rr) * qq) + sidx;
  const int mt = wg / Ntiles, nt = wg % Ntiles;

  const int tid = threadIdx.x;
  const int wid = tid >> 6, lane = tid & 63;
  const int wm = wid >> 2, wn = wid & 3;
  const int c16 = lane & 15, q4 = lane >> 4;
  const int rA_base = wm * 128 + c16;
  const int rB_base = wn * 64 + c16;
  const int caf = (q4 ^ ((lane >> 1) & 3)) << 3;  // chunk slot q4^((row>>1)&3)

  const int sr = tid >> 2;
  const int scol = ((tid & 3) ^ ((tid >> 3) & 3)) << 3;
  const u16* Ar = A + ((size_t)mt * 256 + sr) * K + scol;
  const u16* Br = B + ((size_t)nt * 256 + sr) * K + scol;
  constexpr size_t rstep = (size_t)128 * K;

  f32x4 acc[8][4];
#pragma unroll
  for (int m = 0; m < 8; ++m)
#pragma unroll
    for (int n = 0; n < 4; ++n) acc[m][n] = f32x4{0.f, 0.f, 0.f, 0.f};

#define STAGE(MAT, KK, T, BUF)                                                \
  {                                                                           \
    const u16* g = ((MAT) ? Br : Ar) + (T) * 64 + (KK) * 32;                  \
    u16* l = &lds[BUF][MAT][KK][wid << 9];                                    \
    GLD(g, l);                                                                \
    GLD(g + rstep, l + 4096);                                                 \
  }
#define LDA(DB, KK, MH, AF)                                                   \
  _Pragma("unroll") for (int m = 0; m < 4; ++m)                               \
      AF[m] = *reinterpret_cast<const short8*>(                               \
          &lds[DB][0][KK][(rA_base + ((MH) * 4 + m) * 16) * 32 + caf]);
#define LDB(DB, KK, BF)                                                       \
  _Pragma("unroll") for (int n = 0; n < 4; ++n)                               \
      BF[n] = *reinterpret_cast<const short8*>(                               \
          &lds[DB][1][KK][(rB_base + n * 16) * 32 + caf]);
#define MFMA16(AF, BF, OFS)                                                   \
  __builtin_amdgcn_s_setprio(1);                                              \
  _Pragma("unroll") for (int m = 0; m < 4; ++m)                               \
      _Pragma("unroll") for (int n = 0; n < 4; ++n)                           \
          acc[(OFS) + m][n] = __builtin_amdgcn_mfma_f32_16x16x32_bf16(        \
              AF[m], BF[n], acc[(OFS) + m][n], 0, 0, 0);                      \
  __builtin_amdgcn_s_setprio(0);
#define BARR asm volatile("s_barrier" ::: "memory")
#define VMC(NN) asm volatile("s_waitcnt vmcnt(" #NN ")" ::: "memory")
#define LGKM(NN) do { asm volatile("s_waitcnt lgkmcnt(" #NN ")" ::: "memory");\
                      __builtin_amdgcn_sched_barrier(0); } while (0)

// Phase: consume (DBc,KKc) with frags (BC,A0C) [prefetched last phase] +
// in-phase A1; prefetch (DBn,KKn) -> (BN,A0N); optional stage; waits LG1/LG2.
#define PH(DBc, KKc, DBn, KKn, BC, A0C, BN, A0N, DOPF, DOSTG, STKK, STT,      \
           STBUF, LG1, LG2, DOVM, VMN)                                        \
  {                                                                           \
    LDA(DBc, KKc, 1, a1)                                                      \
    if (DOPF) { LDB(DBn, KKn, BN) LDA(DBn, KKn, 0, A0N) }                     \
    if (DOSTG) { STAGE(0, STKK, STT, STBUF) STAGE(1, STKK, STT, STBUF) }      \
    LGKM(LG1);                                                                \
    MFMA16(A0C, BC, 0)                                                        \
    LGKM(LG2);                                                                \
    MFMA16(a1, BC, 4)                                                         \
    __builtin_amdgcn_sched_barrier(0);                                        \
    if (DOVM) { VMC(VMN); BARR; }                                             \
  }

  // prologue: tile0 (kk0,kk1)->buf0, tile1 kk0 -> buf1 (12 GLDs);
  // vmcnt(4) -> tile0 resident; prime set-A with (buf0,kk0) B+A0 (8 reads).
  STAGE(1, 0, 0, 0) STAGE(0, 0, 0, 0) STAGE(1, 1, 0, 0) STAGE(0, 1, 0, 0)
  STAGE(1, 0, 1, 1) STAGE(0, 0, 1, 1)
  VMC(4);
  BARR;

  short8 bA[4], a0A[4], bB[4], a0B[4], a1[4];
  LDB(0, 0, bA) LDA(0, 0, 0, a0A)

#pragma unroll 1
  for (int u = 0; u < NT - 2; u += 2) {
    // P1: consume tile u kk0 (0,0); pf (0,1)->setB; stage kk1[u+1]->buf1
    PH(0, 0, 0, 1, bA, a0A, bB, a0B, 1, 1, 1, u + 1, 1, 12, 8, 1, 4)
    // P2: consume tile u kk1 (0,1); pf (1,0)->setA; stage kk0[u+2]->buf0
    PH(0, 1, 1, 0, bB, a0B, bA, a0A, 1, 1, 0, u + 2, 0, 12, 8, 1, 4)
    // P3: consume tile u+1 kk0 (1,0); pf (1,1)->setB; stage kk1[u+2]->buf0
    PH(1, 0, 1, 1, bA, a0A, bB, a0B, 1, 1, 1, u + 2, 0, 12, 8, 1, 4)
    // P4: consume tile u+1 kk1 (1,1); pf (0,0)->setA; stage kk0[u+3]->buf1
    PH(1, 1, 0, 0, bB, a0B, bA, a0A, 1, 1, 0, u + 3, 1, 12, 8, 1, 4)
  }
  // tail: tiles NT-2 (buf0), NT-1 (buf1)
  PH(0, 0, 0, 1, bA, a0A, bB, a0B, 1, 1, 1, NT - 1, 1, 12, 8, 1, 4)  // stage kk1[NT-1]
  PH(0, 1, 1, 0, bB, a0B, bA, a0A, 1, 0, 0, 0, 0, 12, 8, 1, 0)       // drain vmcnt(0)
  PH(1, 0, 1, 1, bA, a0A, bB, a0B, 1, 0, 0, 0, 0, 12, 8, 1, 0)
  PH(1, 1, 0, 0, bB, a0B, bA, a0A, 0, 0, 0, 0, 0, 4, 0, 0, 0)        // final

  // ---- epilogue
  const int mbase0 = mt * 256 + wm * 128;
  if constexpr (GATE == 0) {
#pragma unroll
    for (int m = 0; m < 8; ++m) {
#pragma unroll
      for (int j = 0; j < 4; ++j) {
        const int row = mbase0 + m * 16 + q4 * 4 + j;
        const float sc = rowscale[row];
        float* crow = C + (size_t)row * N + nt * 256 + wn * 64 + c16;
#pragma unroll
        for (int n = 0; n < 4; ++n) crow[n * 16] = acc[m][n][j] * sc;
      }
    }
  } else {
    constexpr int H = N >> 1;
    const int gbase = (nt * 256 + wn * 64) >> 1;
#pragma unroll
    for (int m = 0; m < 8; ++m) {
#pragma unroll
      for (int j = 0; j < 4; ++j) {
        const int row = mbase0 + m * 16 + q4 * 4 + j;
        const float sc = rowscale[row];
        const float s3 = sc * sc * sc;
        float* grow = C + (size_t)row * H + gbase + c16;
#pragma unroll
        for (int p = 0; p < 2; ++p) {
          float a1v = acc[m][2 * p][j];
          float a3v = acc[m][2 * p + 1][j];
          float rl = fmaxf(a1v, 0.f);
          grow[p * 16] = rl * rl * a3v * s3;
        }
      }
    }
  }
}

extern "C" void kernel_launch(void* const* d_in, const int* in_sizes, int n_in,
                              void* d_out, int out_size, void* d_ws, size_t ws_size,
                              hipStream_t stream) {
  const float* x = (const float*)d_in[0];
  const float* w13 = (const float*)d_in[1];
  const float* w2 = (const float*)d_in[2];
  const float* nw = (const float*)d_in[3];
  float* out = (float*)d_out;

  char* p = (char*)d_ws;
  u16* w13p = (u16*)p; p += (size_t)F2 * DIM * 2;
  u16* w2b = (u16*)p;  p += (size_t)DIM * HID * 2;
  u16* q2f = (u16*)p;  p += (size_t)TTOT * HID * 2;
  float* s2f = (float*)p; p += (size_t)TTOT * 4;
  const size_t fixed = (size_t)F2 * DIM * 2 + (size_t)DIM * HID * 2 +
                       (size_t)TTOT * HID * 2 + (size_t)TTOT * 4;
  const size_t perTok = (size_t)DIM * 2 + (size_t)HID * 4 + 8;
  int Tc = TTOT;
  while (Tc > 256 && fixed + (size_t)Tc * perTok > ws_size) Tc >>= 1;
  u16* q1 = (u16*)p;        p += (size_t)Tc * DIM * 2;
  float* gated = (float*)p; p += (size_t)Tc * HID * 4;
  float* s1 = (float*)p;

  conv_w13<<<F2 * DIM / 4 / 256, 256, 0, stream>>>(w13, w13p);
  conv_w2<<<DIM * HID / 4 / 256, 256, 0, stream>>>(w2, w2b);

  for (int t0 = 0; t0 < TTOT; t0 += Tc) {
    quant_x<<<Tc, 256, 0, stream>>>(x + (size_t)t0 * DIM, q1, s1);
    gemm8<1, F2, DIM, F2 / 256><<<(Tc / 256) * (F2 / 256), 512, 0, stream>>>(
        q1, w13p, s1, gated);
    gate_nq<<<Tc, 256, 0, stream>>>(gated, nw, q2f + (size_t)t0 * HID, s2f + t0);
  }
  gemm8<0, DIM, HID, DIM / 256><<<(TTOT / 256) * (DIM / 256), 512, 0, stream>>>(
      q2f, w2b, s2f, out);
}